// Round 8
// baseline (236.406 us; speedup 1.0000x reference)
//
#include <hip/hip_runtime.h>
#include <hip/hip_bf16.h>
#include <math.h>

// Problem constants (B,D,N from reference)
#define MDIM 4096   // batch rows
#define KDIM 2048   // feature dim D
#define NDIM 4096   // output dim N
#define DT   0.01f
#define TWO_PI_F 6.283185307179586f
#define CH 64       // scan chunks
#define CL 64       // steps per chunk  (CH*CL == MDIM)

typedef __attribute__((ext_vector_type(8))) short bf16x8;
typedef __attribute__((ext_vector_type(4))) float f32x4;

__device__ __forceinline__ unsigned short f2bf(float f) {
  unsigned int u = __float_as_uint(f);
  u += 0x7FFFu + ((u >> 16) & 1u);           // round-to-nearest-even
  return (unsigned short)(u >> 16);
}
__device__ __forceinline__ float bf2f(unsigned short u) {
  return __uint_as_float(((unsigned int)u) << 16);
}

// -------- fused cast fp32 -> bf16 for x and W (both 8M floats) --------
__global__ void cast2_bf16_kernel(const float* __restrict__ s0,
                                  unsigned short* __restrict__ d0,
                                  const float* __restrict__ s1,
                                  unsigned short* __restrict__ d1,
                                  int n4each) {
  int i = blockIdx.x * blockDim.x + threadIdx.x;
  const float4* sp;
  ushort4* dp;
  int j;
  if (i < n4each) { sp = (const float4*)s0; dp = (ushort4*)d0; j = i; }
  else            { sp = (const float4*)s1; dp = (ushort4*)d1; j = i - n4each; }
  float4 v = sp[j];
  ushort4 o;
  o.x = f2bf(v.x); o.y = f2bf(v.y); o.z = f2bf(v.z); o.w = f2bf(v.w);
  dp[j] = o;
}

// ============ FUSED PATH: GEMM + pass1 epilogue (needs 66 MiB ws) ============
// GEMM core identical to round-7 (BK=32, XOR-swizzled LDS, 0 bank conflicts).
// Epilogue per wave: C-tile -> row-major LDS (bias added, bf16), lane n scans
// column n over the 64-row chunk (zero init) -> zpart bf16 + fp32 partials.
__global__ __launch_bounds__(256, 2) void gemm_scan_kernel(
    const unsigned short* __restrict__ A,
    const unsigned short* __restrict__ Bm,
    const float* __restrict__ bias,
    const float* __restrict__ freq,
    const float* __restrict__ damp,
    unsigned short* __restrict__ zpart,
    float* __restrict__ chunkS,
    float* __restrict__ chunkV) {
  __shared__ __align__(16) unsigned short smem[16384];   // 32 KB
  unsigned short* sA = smem;           // [128*32] staging
  unsigned short* sB = smem + 4096;    // [128*32] staging

  const int tid  = threadIdx.x;
  const int lane = tid & 63;
  const int wave = tid >> 6;
  const int wr = wave >> 1;
  const int wc = wave & 1;
  const int q  = lane >> 4;
  const int lm = lane & 15;

  const int bM = blockIdx.x * 128;
  const int bN = blockIdx.y * 128;

  f32x4 acc[4][4];
#pragma unroll
  for (int i = 0; i < 4; i++)
#pragma unroll
    for (int j = 0; j < 4; j++) acc[i][j] = (f32x4){0.f, 0.f, 0.f, 0.f};

  const int idx0 = tid;
  const int idx1 = tid + 256;
  const int r0 = idx0 >> 2, g0 = idx0 & 3;
  const int r1 = idx1 >> 2, g1 = idx1 & 3;
  const int dst0 = r0 * 32 + ((g0 ^ ((r0 >> 1) & 3)) * 8);
  const int dst1 = r1 * 32 + ((g1 ^ ((r1 >> 1) & 3)) * 8);
  const unsigned short* gA0 = A  + (size_t)(bM + r0) * KDIM + g0 * 8;
  const unsigned short* gA1 = A  + (size_t)(bM + r1) * KDIM + g1 * 8;
  const unsigned short* gB0 = Bm + (size_t)(bN + r0) * KDIM + g0 * 8;
  const unsigned short* gB1 = Bm + (size_t)(bN + r1) * KDIM + g1 * 8;
  const int rq = (q ^ ((lm >> 1) & 3)) * 8;

  for (int k0 = 0; k0 < KDIM; k0 += 32) {
    uint4 av0 = *(const uint4*)(gA0 + k0);
    uint4 av1 = *(const uint4*)(gA1 + k0);
    uint4 bv0 = *(const uint4*)(gB0 + k0);
    uint4 bv1 = *(const uint4*)(gB1 + k0);
    __syncthreads();
    *(uint4*)&sA[dst0] = av0;
    *(uint4*)&sA[dst1] = av1;
    *(uint4*)&sB[dst0] = bv0;
    *(uint4*)&sB[dst1] = bv1;
    __syncthreads();

    bf16x8 af[4], bfr[4];
#pragma unroll
    for (int mt = 0; mt < 4; mt++)
      af[mt]  = *(const bf16x8*)&sA[(wr * 64 + mt * 16 + lm) * 32 + rq];
#pragma unroll
    for (int nt = 0; nt < 4; nt++)
      bfr[nt] = *(const bf16x8*)&sB[(wc * 64 + nt * 16 + lm) * 32 + rq];

#pragma unroll
    for (int mt = 0; mt < 4; mt++)
#pragma unroll
      for (int nt = 0; nt < 4; nt++)
        acc[mt][nt] = __builtin_amdgcn_mfma_f32_16x16x32_bf16(
            af[mt], bfr[nt], acc[mt][nt], 0, 0, 0);
  }

  // ---- epilogue: transpose to row-major LDS (bias added), R5-validated ----
  __syncthreads();                 // staging reads done; safe to reuse smem
  unsigned short* sT = smem + wave * 4096;    // 64x64 bf16 per wave
#pragma unroll
  for (int nt = 0; nt < 4; nt++) {
    const float bz = bias[bN + wc * 64 + nt * 16 + lm];
#pragma unroll
    for (int mt = 0; mt < 4; mt++)
#pragma unroll
      for (int r = 0; r < 4; r++)
        sT[(mt * 16 + q * 4 + r) * 64 + nt * 16 + lm] =
            f2bf(acc[mt][nt][r] + bz);
  }
  __syncthreads();

  // lane n scans column n of this wave's chunk (zero init)
  const int gcol = bN + wc * 64 + lane;
  const float om  = TWO_PI_F * freq[gcol];
  const float osq = om * om;
  const float dp  = damp[gcol];
  float s = 0.f, v = 0.f;
#pragma unroll 8
  for (int i = 0; i < CL; i++) {
    float f = bf2f(sT[i * 64 + lane]);
    v += (-osq * s - dp * v + f) * DT;
    s += v * DT;
    sT[i * 64 + lane] = f2bf(s);   // in-place: zpart (columns disjoint/lane)
  }
  const int chunk = 2 * blockIdx.x + wr;
  chunkS[chunk * NDIM + gcol] = s;
  chunkV[chunk * NDIM + gcol] = v;
  __syncthreads();

  // coalesced writeback of 64x64 bf16 zpart tile
#pragma unroll
  for (int k = 0; k < 8; k++) {
    int slot = lane + 64 * k;
    int row  = slot >> 3;
    int col8 = (slot & 7) * 8;
    *(uint4*)&zpart[(size_t)(bM + wr * 64 + row) * NDIM + bN + wc * 64 + col8] =
        *(uint4*)&sT[row * 64 + col8];
  }
}

// ---- fused path kernel 2: lookback carry + homogeneous replay (R5-proven) --
__global__ void scan_out_kernel(const unsigned short* __restrict__ zpart,
                                const float* __restrict__ amp,
                                const float* __restrict__ freq,
                                const float* __restrict__ phase,
                                const float* __restrict__ damp,
                                const float* __restrict__ chunkS,
                                const float* __restrict__ chunkV,
                                float* __restrict__ out) {
  int gid = blockIdx.x * blockDim.x + threadIdx.x;
  int n4 = gid & (NDIM / 4 - 1);
  int c  = gid >> 10;
  int n  = n4 * 4;

  float4 fr = *(const float4*)&freq[n];
  float4 dv = *(const float4*)&damp[n];
  float4 am = *(const float4*)&amp[n];
  float4 ph = *(const float4*)&phase[n];
  float omv[4] = {TWO_PI_F * fr.x, TWO_PI_F * fr.y, TWO_PI_F * fr.z, TWO_PI_F * fr.w};
  float dpv[4] = {dv.x, dv.y, dv.z, dv.w};
  float amv[4] = {am.x, am.y, am.z, am.w};
  float phv[4] = {ph.x, ph.y, ph.z, ph.w};
  float m00[4], m01[4], m10[4], m11[4];
  float p00[4], p01[4], p10[4], p11[4];
  float osc[4];
#pragma unroll
  for (int j = 0; j < 4; j++) {
    float osq = omv[j] * omv[j];
    m00[j] = 1.f - osq * DT * DT;  m01[j] = DT * (1.f - dpv[j] * DT);
    m10[j] = -osq * DT;            m11[j] = 1.f - dpv[j] * DT;
    p00[j] = m00[j]; p01[j] = m01[j]; p10[j] = m10[j]; p11[j] = m11[j];
    osc[j] = amv[j] * sinf(omv[j] * DT + phv[j]);    // t = DT
  }
#pragma unroll
  for (int i = 0; i < 6; i++)                         // M^64 by squaring
#pragma unroll
    for (int j = 0; j < 4; j++) {
      float b00 = p00[j] * p00[j] + p01[j] * p10[j];
      float b01 = p00[j] * p01[j] + p01[j] * p11[j];
      float b10 = p10[j] * p00[j] + p11[j] * p10[j];
      float b11 = p10[j] * p01[j] + p11[j] * p11[j];
      p00[j] = b00; p01[j] = b01; p10[j] = b10; p11[j] = b11;
    }

  float hs[4] = {0.f, 0.f, 0.f, 0.f}, hv[4] = {0.f, 0.f, 0.f, 0.f};
  for (int cc = 0; cc < c; cc++) {
    float4 ls = *(const float4*)&chunkS[cc * NDIM + n];
    float4 lv = *(const float4*)&chunkV[cc * NDIM + n];
    float lsv[4] = {ls.x, ls.y, ls.z, ls.w};
    float lvv[4] = {lv.x, lv.y, lv.z, lv.w};
#pragma unroll
    for (int j = 0; j < 4; j++) {
      float t = p00[j] * hs[j] + p01[j] * hv[j] + lsv[j];
      float u = p10[j] * hs[j] + p11[j] * hv[j] + lvv[j];
      hs[j] = t; hv[j] = u;
    }
  }

  const unsigned short* zp = zpart + (size_t)c * CL * NDIM + n;
  float* op = out + (size_t)c * CL * NDIM + n;
#pragma unroll 4
  for (int i = 0; i < CL; i++) {
    ushort4 zv = *(const ushort4*)&zp[(size_t)i * NDIM];
    float z[4] = {bf2f(zv.x), bf2f(zv.y), bf2f(zv.z), bf2f(zv.w)};
    float o[4];
#pragma unroll
    for (int j = 0; j < 4; j++) {
      float t = m00[j] * hs[j] + m01[j] * hv[j];
      float u = m10[j] * hs[j] + m11[j] * hv[j];
      hs[j] = t; hv[j] = u;
      o[j] = fminf(1.f, fmaxf(-1.f, hs[j] + z[j] + osc[j]));
    }
    *(float4*)&op[(size_t)i * NDIM] = (float4){o[0], o[1], o[2], o[3]};
  }
}

// ============ FALLBACK PATH: exact round-7 pipeline (64 MiB ws) ============
__global__ __launch_bounds__(256, 2) void gemm_bt_kernel(
    const unsigned short* __restrict__ A,
    const unsigned short* __restrict__ Bm,
    const float* __restrict__ bias,
    unsigned short* __restrict__ C) {
  __shared__ __align__(16) unsigned short sA[128 * 32];
  __shared__ __align__(16) unsigned short sB[128 * 32];

  const int tid  = threadIdx.x;
  const int lane = tid & 63;
  const int wave = tid >> 6;
  const int wr = wave >> 1;
  const int wc = wave & 1;
  const int q  = lane >> 4;
  const int lm = lane & 15;

  const int bM = blockIdx.x * 128;
  const int bN = blockIdx.y * 128;

  f32x4 acc[4][4];
#pragma unroll
  for (int i = 0; i < 4; i++)
#pragma unroll
    for (int j = 0; j < 4; j++) acc[i][j] = (f32x4){0.f, 0.f, 0.f, 0.f};

  const int idx0 = tid;
  const int idx1 = tid + 256;
  const int r0 = idx0 >> 2, g0 = idx0 & 3;
  const int r1 = idx1 >> 2, g1 = idx1 & 3;
  const int dst0 = r0 * 32 + ((g0 ^ ((r0 >> 1) & 3)) * 8);
  const int dst1 = r1 * 32 + ((g1 ^ ((r1 >> 1) & 3)) * 8);
  const unsigned short* gA0 = A  + (size_t)(bM + r0) * KDIM + g0 * 8;
  const unsigned short* gA1 = A  + (size_t)(bM + r1) * KDIM + g1 * 8;
  const unsigned short* gB0 = Bm + (size_t)(bN + r0) * KDIM + g0 * 8;
  const unsigned short* gB1 = Bm + (size_t)(bN + r1) * KDIM + g1 * 8;
  const int rq = (q ^ ((lm >> 1) & 3)) * 8;

  for (int k0 = 0; k0 < KDIM; k0 += 32) {
    uint4 av0 = *(const uint4*)(gA0 + k0);
    uint4 av1 = *(const uint4*)(gA1 + k0);
    uint4 bv0 = *(const uint4*)(gB0 + k0);
    uint4 bv1 = *(const uint4*)(gB1 + k0);
    __syncthreads();
    *(uint4*)&sA[dst0] = av0;
    *(uint4*)&sA[dst1] = av1;
    *(uint4*)&sB[dst0] = bv0;
    *(uint4*)&sB[dst1] = bv1;
    __syncthreads();

    bf16x8 af[4], bfr[4];
#pragma unroll
    for (int mt = 0; mt < 4; mt++)
      af[mt]  = *(const bf16x8*)&sA[(wr * 64 + mt * 16 + lm) * 32 + rq];
#pragma unroll
    for (int nt = 0; nt < 4; nt++)
      bfr[nt] = *(const bf16x8*)&sB[(wc * 64 + nt * 16 + lm) * 32 + rq];

#pragma unroll
    for (int mt = 0; mt < 4; mt++)
#pragma unroll
      for (int nt = 0; nt < 4; nt++)
        acc[mt][nt] = __builtin_amdgcn_mfma_f32_16x16x32_bf16(
            af[mt], bfr[nt], acc[mt][nt], 0, 0, 0);
  }

#pragma unroll
  for (int nt = 0; nt < 4; nt++) {
    const int col = bN + wc * 64 + nt * 16 + lm;
    const float bz = bias[col];
#pragma unroll
    for (int mt = 0; mt < 4; mt++) {
      const int row0 = bM + wr * 64 + mt * 16 + q * 4;
#pragma unroll
      for (int r = 0; r < 4; r++)
        C[(size_t)(row0 + r) * NDIM + col] = f2bf(acc[mt][nt][r] + bz);
    }
  }
}

__global__ void scan_pass1(const unsigned short* __restrict__ force,
                           const float* __restrict__ freq,
                           const float* __restrict__ damp,
                           float* __restrict__ chunkS,
                           float* __restrict__ chunkV) {
  int gid = blockIdx.x * blockDim.x + threadIdx.x;
  int n4 = gid & (NDIM / 4 - 1);
  int c  = gid >> 10;
  int n  = n4 * 4;
  float4 fr = *(const float4*)&freq[n];
  float4 dv = *(const float4*)&damp[n];
  float osq[4] = {TWO_PI_F * fr.x, TWO_PI_F * fr.y, TWO_PI_F * fr.z, TWO_PI_F * fr.w};
  float dp[4]  = {dv.x, dv.y, dv.z, dv.w};
  float s[4] = {0.f, 0.f, 0.f, 0.f}, v[4] = {0.f, 0.f, 0.f, 0.f};
#pragma unroll
  for (int j = 0; j < 4; j++) osq[j] *= osq[j];
  const unsigned short* fp = force + (size_t)c * CL * NDIM + n;
#pragma unroll 4
  for (int i = 0; i < CL; i++) {
    ushort4 fv = *(const ushort4*)&fp[(size_t)i * NDIM];
    float f[4] = {bf2f(fv.x), bf2f(fv.y), bf2f(fv.z), bf2f(fv.w)};
#pragma unroll
    for (int j = 0; j < 4; j++) {
      float a = -osq[j] * s[j] - dp[j] * v[j] + f[j];
      v[j] += a * DT;
      s[j] += v[j] * DT;
    }
  }
  *(float4*)&chunkS[c * NDIM + n] = (float4){s[0], s[1], s[2], s[3]};
  *(float4*)&chunkV[c * NDIM + n] = (float4){v[0], v[1], v[2], v[3]};
}

__global__ void scan_pass2(const float* __restrict__ chunkS,
                           const float* __restrict__ chunkV,
                           const float* __restrict__ freq,
                           const float* __restrict__ damp,
                           float* __restrict__ carryS,
                           float* __restrict__ carryV) {
  int n = blockIdx.x * blockDim.x + threadIdx.x;
  float om = TWO_PI_F * freq[n];
  float osq = om * om;
  float dp = damp[n];
  float a00 = 1.f - osq * DT * DT, a01 = DT * (1.f - dp * DT);
  float a10 = -osq * DT,           a11 = 1.f - dp * DT;
#pragma unroll
  for (int i = 0; i < 6; i++) {
    float b00 = a00 * a00 + a01 * a10;
    float b01 = a00 * a01 + a01 * a11;
    float b10 = a10 * a00 + a11 * a10;
    float b11 = a10 * a01 + a11 * a11;
    a00 = b00; a01 = b01; a10 = b10; a11 = b11;
  }
  float cs = 0.f, cv = 0.f;
#pragma unroll 8
  for (int c = 0; c < CH; c++) {
    carryS[c * NDIM + n] = cs;
    carryV[c * NDIM + n] = cv;
    float ls = chunkS[c * NDIM + n];
    float lv = chunkV[c * NDIM + n];
    float ns = a00 * cs + a01 * cv + ls;
    float nv = a10 * cs + a11 * cv + lv;
    cs = ns; cv = nv;
  }
}

__global__ void scan_pass3(const unsigned short* __restrict__ force,
                           const float* __restrict__ amp,
                           const float* __restrict__ freq,
                           const float* __restrict__ phase,
                           const float* __restrict__ damp,
                           const float* __restrict__ carryS,
                           const float* __restrict__ carryV,
                           float* __restrict__ out) {
  int gid = blockIdx.x * blockDim.x + threadIdx.x;
  int n4 = gid & (NDIM / 4 - 1);
  int c  = gid >> 10;
  int n  = n4 * 4;
  float4 fr = *(const float4*)&freq[n];
  float4 dv = *(const float4*)&damp[n];
  float4 am = *(const float4*)&amp[n];
  float4 ph = *(const float4*)&phase[n];
  float om[4] = {TWO_PI_F * fr.x, TWO_PI_F * fr.y, TWO_PI_F * fr.z, TWO_PI_F * fr.w};
  float dp[4] = {dv.x, dv.y, dv.z, dv.w};
  float osq[4], osc[4], s[4], v[4];
  float amv[4] = {am.x, am.y, am.z, am.w};
  float phv[4] = {ph.x, ph.y, ph.z, ph.w};
#pragma unroll
  for (int j = 0; j < 4; j++) {
    osq[j] = om[j] * om[j];
    osc[j] = amv[j] * sinf(om[j] * DT + phv[j]);
  }
  float4 csv = *(const float4*)&carryS[c * NDIM + n];
  float4 cvv = *(const float4*)&carryV[c * NDIM + n];
  s[0] = csv.x; s[1] = csv.y; s[2] = csv.z; s[3] = csv.w;
  v[0] = cvv.x; v[1] = cvv.y; v[2] = cvv.z; v[3] = cvv.w;
  const unsigned short* fp = force + (size_t)c * CL * NDIM + n;
  float* op = out + (size_t)c * CL * NDIM + n;
#pragma unroll 4
  for (int i = 0; i < CL; i++) {
    ushort4 fv = *(const ushort4*)&fp[(size_t)i * NDIM];
    float f[4] = {bf2f(fv.x), bf2f(fv.y), bf2f(fv.z), bf2f(fv.w)};
    float o[4];
#pragma unroll
    for (int j = 0; j < 4; j++) {
      float a = -osq[j] * s[j] - dp[j] * v[j] + f[j];
      v[j] += a * DT;
      s[j] += v[j] * DT;
      o[j] = fminf(1.f, fmaxf(-1.f, s[j] + osc[j]));
    }
    *(float4*)&op[(size_t)i * NDIM] = (float4){o[0], o[1], o[2], o[3]};
  }
}

// ---------------- launch ----------------
extern "C" void kernel_launch(void* const* d_in, const int* in_sizes, int n_in,
                              void* d_out, int out_size, void* d_ws, size_t ws_size,
                              hipStream_t stream) {
  const float* x     = (const float*)d_in[0];
  const float* W     = (const float*)d_in[1];
  const float* bias  = (const float*)d_in[2];
  const float* amp   = (const float*)d_in[3];
  const float* freq  = (const float*)d_in[4];
  const float* phase = (const float*)d_in[5];
  const float* damp  = (const float*)d_in[6];

  const size_t MiB = 1024 * 1024;
  const int n4each = MDIM * KDIM / 4;
  dim3 gg(MDIM / 128, NDIM / 128);

  if (ws_size >= 66 * MiB) {
    // fused path: xbf[0,16Mi) wbf[16,32Mi) zpart[32,64Mi) chunks[64,66Mi)
    unsigned short* xbf   = (unsigned short*)d_ws;
    unsigned short* wbf   = xbf + (size_t)MDIM * KDIM;
    unsigned short* zpart = wbf + (size_t)NDIM * KDIM;
    float* chunkS = (float*)((char*)d_ws + 64 * MiB);
    float* chunkV = chunkS + CH * NDIM;

    cast2_bf16_kernel<<<(2 * n4each + 255) / 256, 256, 0, stream>>>(
        x, xbf, W, wbf, n4each);
    gemm_scan_kernel<<<gg, 256, 0, stream>>>(xbf, wbf, bias, freq, damp,
                                             zpart, chunkS, chunkV);
    scan_out_kernel<<<CH * NDIM / 4 / 256, 256, 0, stream>>>(
        zpart, amp, freq, phase, damp, chunkS, chunkV, (float*)d_out);
  } else {
    // fallback: exact round-7 pipeline (proven, 64 MiB)
    unsigned short* xbf   = (unsigned short*)d_ws;
    unsigned short* wbf   = xbf + (size_t)MDIM * KDIM;
    unsigned short* force = wbf + (size_t)NDIM * KDIM;
    float* chunkS = (float*)d_ws;            // aliases xbf: dead after GEMM
    float* chunkV = chunkS + CH * NDIM;
    float* carryS = chunkV + CH * NDIM;
    float* carryV = carryS + CH * NDIM;

    cast2_bf16_kernel<<<(2 * n4each + 255) / 256, 256, 0, stream>>>(
        x, xbf, W, wbf, n4each);
    gemm_bt_kernel<<<gg, 256, 0, stream>>>(xbf, wbf, bias, force);
    scan_pass1<<<CH * NDIM / 4 / 256, 256, 0, stream>>>(force, freq, damp,
                                                        chunkS, chunkV);
    scan_pass2<<<NDIM / 256, 256, 0, stream>>>(chunkS, chunkV, freq, damp,
                                               carryS, carryV);
    scan_pass3<<<CH * NDIM / 4 / 256, 256, 0, stream>>>(
        force, amp, freq, phase, damp, carryS, carryV, (float*)d_out);
  }
}

// Round 9
// 224.040 us; speedup vs baseline: 1.0552x; 1.0552x over previous
//
#include <hip/hip_runtime.h>
#include <hip/hip_bf16.h>
#include <math.h>

// Problem constants (B,D,N from reference)
#define MDIM 4096   // batch rows
#define KDIM 2048   // feature dim D
#define NDIM 4096   // output dim N
#define DT   0.01f
#define TWO_PI_F 6.283185307179586f
#define CH 64       // scan chunks
#define CL 64       // steps per chunk  (CH*CL == MDIM)

typedef __attribute__((ext_vector_type(8))) short bf16x8;
typedef __attribute__((ext_vector_type(4))) float f32x4;

__device__ __forceinline__ unsigned short f2bf(float f) {
  unsigned int u = __float_as_uint(f);
  u += 0x7FFFu + ((u >> 16) & 1u);           // round-to-nearest-even
  return (unsigned short)(u >> 16);
}
__device__ __forceinline__ float bf2f(unsigned short u) {
  return __uint_as_float(((unsigned int)u) << 16);
}

// -------- fused cast fp32 -> bf16 for x and W (both 8M floats) --------
__global__ void cast2_bf16_kernel(const float* __restrict__ s0,
                                  unsigned short* __restrict__ d0,
                                  const float* __restrict__ s1,
                                  unsigned short* __restrict__ d1,
                                  int n4each) {
  int i = blockIdx.x * blockDim.x + threadIdx.x;
  const float4* sp;
  ushort4* dp;
  int j;
  if (i < n4each) { sp = (const float4*)s0; dp = (ushort4*)d0; j = i; }
  else            { sp = (const float4*)s1; dp = (ushort4*)d1; j = i - n4each; }
  float4 v = sp[j];
  ushort4 o;
  o.x = f2bf(v.x); o.y = f2bf(v.y); o.z = f2bf(v.z); o.w = f2bf(v.w);
  dp[j] = o;
}

// ============ FUSED PATH: GEMM + pass1 epilogue (needs 66 MiB ws) ============
// GEMM core = round-7 (BK=32, XOR-swizzled LDS, 0 bank conflicts). Epilogue:
// C-tile -> row-major LDS (bias added, bf16); lane n scans column n over the
// 64-row chunk (zero init) -> zpart bf16 + fp32 chunk partials. Measured
// 92.2 us (R8) ~= GEMM-only 91: epilogue is essentially free.
__global__ __launch_bounds__(256, 2) void gemm_scan_kernel(
    const unsigned short* __restrict__ A,
    const unsigned short* __restrict__ Bm,
    const float* __restrict__ bias,
    const float* __restrict__ freq,
    const float* __restrict__ damp,
    unsigned short* __restrict__ zpart,
    float* __restrict__ chunkS,
    float* __restrict__ chunkV) {
  __shared__ __align__(16) unsigned short smem[16384];   // 32 KB
  unsigned short* sA = smem;           // [128*32] staging
  unsigned short* sB = smem + 4096;    // [128*32] staging

  const int tid  = threadIdx.x;
  const int lane = tid & 63;
  const int wave = tid >> 6;
  const int wr = wave >> 1;
  const int wc = wave & 1;
  const int q  = lane >> 4;
  const int lm = lane & 15;

  const int bM = blockIdx.x * 128;
  const int bN = blockIdx.y * 128;

  f32x4 acc[4][4];
#pragma unroll
  for (int i = 0; i < 4; i++)
#pragma unroll
    for (int j = 0; j < 4; j++) acc[i][j] = (f32x4){0.f, 0.f, 0.f, 0.f};

  const int idx0 = tid;
  const int idx1 = tid + 256;
  const int r0 = idx0 >> 2, g0 = idx0 & 3;
  const int r1 = idx1 >> 2, g1 = idx1 & 3;
  const int dst0 = r0 * 32 + ((g0 ^ ((r0 >> 1) & 3)) * 8);
  const int dst1 = r1 * 32 + ((g1 ^ ((r1 >> 1) & 3)) * 8);
  const unsigned short* gA0 = A  + (size_t)(bM + r0) * KDIM + g0 * 8;
  const unsigned short* gA1 = A  + (size_t)(bM + r1) * KDIM + g1 * 8;
  const unsigned short* gB0 = Bm + (size_t)(bN + r0) * KDIM + g0 * 8;
  const unsigned short* gB1 = Bm + (size_t)(bN + r1) * KDIM + g1 * 8;
  const int rq = (q ^ ((lm >> 1) & 3)) * 8;

  for (int k0 = 0; k0 < KDIM; k0 += 32) {
    uint4 av0 = *(const uint4*)(gA0 + k0);
    uint4 av1 = *(const uint4*)(gA1 + k0);
    uint4 bv0 = *(const uint4*)(gB0 + k0);
    uint4 bv1 = *(const uint4*)(gB1 + k0);
    __syncthreads();
    *(uint4*)&sA[dst0] = av0;
    *(uint4*)&sA[dst1] = av1;
    *(uint4*)&sB[dst0] = bv0;
    *(uint4*)&sB[dst1] = bv1;
    __syncthreads();

    bf16x8 af[4], bfr[4];
#pragma unroll
    for (int mt = 0; mt < 4; mt++)
      af[mt]  = *(const bf16x8*)&sA[(wr * 64 + mt * 16 + lm) * 32 + rq];
#pragma unroll
    for (int nt = 0; nt < 4; nt++)
      bfr[nt] = *(const bf16x8*)&sB[(wc * 64 + nt * 16 + lm) * 32 + rq];

#pragma unroll
    for (int mt = 0; mt < 4; mt++)
#pragma unroll
      for (int nt = 0; nt < 4; nt++)
        acc[mt][nt] = __builtin_amdgcn_mfma_f32_16x16x32_bf16(
            af[mt], bfr[nt], acc[mt][nt], 0, 0, 0);
  }

  // ---- epilogue: transpose to row-major LDS (bias added) ----
  __syncthreads();                 // staging reads done; safe to reuse smem
  unsigned short* sT = smem + wave * 4096;    // 64x64 bf16 per wave
#pragma unroll
  for (int nt = 0; nt < 4; nt++) {
    const float bz = bias[bN + wc * 64 + nt * 16 + lm];
#pragma unroll
    for (int mt = 0; mt < 4; mt++)
#pragma unroll
      for (int r = 0; r < 4; r++)
        sT[(mt * 16 + q * 4 + r) * 64 + nt * 16 + lm] =
            f2bf(acc[mt][nt][r] + bz);
  }
  __syncthreads();

  // lane n scans column n of this wave's chunk (zero init)
  const int gcol = bN + wc * 64 + lane;
  const float om  = TWO_PI_F * freq[gcol];
  const float osq = om * om;
  const float dp  = damp[gcol];
  float s = 0.f, v = 0.f;
#pragma unroll 8
  for (int i = 0; i < CL; i++) {
    float f = bf2f(sT[i * 64 + lane]);
    v += (-osq * s - dp * v + f) * DT;
    s += v * DT;
    sT[i * 64 + lane] = f2bf(s);   // in-place: zpart (columns disjoint/lane)
  }
  const int chunk = 2 * blockIdx.x + wr;
  chunkS[chunk * NDIM + gcol] = s;
  chunkV[chunk * NDIM + gcol] = v;
  __syncthreads();

  // coalesced writeback of 64x64 bf16 zpart tile
#pragma unroll
  for (int k = 0; k < 8; k++) {
    int slot = lane + 64 * k;
    int row  = slot >> 3;
    int col8 = (slot & 7) * 8;
    *(uint4*)&zpart[(size_t)(bM + wr * 64 + row) * NDIM + bN + wc * 64 + col8] =
        *(uint4*)&sT[row * 64 + col8];
  }
}

// ---- pass2 IN-PLACE: chunk partials -> carries (same array, 2 MB, ~2 us) ---
// carry[c] = state entering chunk c. Read chunk[c] BEFORE overwriting with
// carry[c], so carryS/V alias chunkS/V and ws stays at 66 MiB.
__global__ void scan_pass2_inplace(float* __restrict__ chunkS,
                                   float* __restrict__ chunkV,
                                   const float* __restrict__ freq,
                                   const float* __restrict__ damp) {
  int n = blockIdx.x * blockDim.x + threadIdx.x;     // 0..NDIM-1
  float om = TWO_PI_F * freq[n];
  float osq = om * om;
  float dp = damp[n];
  float a00 = 1.f - osq * DT * DT, a01 = DT * (1.f - dp * DT);
  float a10 = -osq * DT,           a11 = 1.f - dp * DT;
#pragma unroll
  for (int i = 0; i < 6; i++) {                      // M^64 by squaring
    float b00 = a00 * a00 + a01 * a10;
    float b01 = a00 * a01 + a01 * a11;
    float b10 = a10 * a00 + a11 * a10;
    float b11 = a10 * a01 + a11 * a11;
    a00 = b00; a01 = b01; a10 = b10; a11 = b11;
  }
  float cs = 0.f, cv = 0.f;
#pragma unroll 8
  for (int c = 0; c < CH; c++) {
    float ls = chunkS[c * NDIM + n];                 // read before overwrite
    float lv = chunkV[c * NDIM + n];
    chunkS[c * NDIM + n] = cs;
    chunkV[c * NDIM + n] = cv;
    float ns = a00 * cs + a01 * cv + ls;
    float nv = a10 * cs + a11 * cv + lv;
    cs = ns; cv = nv;
  }
}

// ---- kernel 3: carry load + homogeneous replay + osc/clip, fp32 out ----
// out[c*CL+i][n] = clip( (M^{i+1} carry_c).s + zpart[c*CL+i][n] + osc[n] )
__global__ void scan_out_carry(const unsigned short* __restrict__ zpart,
                               const float* __restrict__ amp,
                               const float* __restrict__ freq,
                               const float* __restrict__ phase,
                               const float* __restrict__ damp,
                               const float* __restrict__ carryS,
                               const float* __restrict__ carryV,
                               float* __restrict__ out) {
  int gid = blockIdx.x * blockDim.x + threadIdx.x;   // 0 .. CH*NDIM/4
  int n4 = gid & (NDIM / 4 - 1);
  int c  = gid >> 10;
  int n  = n4 * 4;

  float4 fr = *(const float4*)&freq[n];
  float4 dv = *(const float4*)&damp[n];
  float4 am = *(const float4*)&amp[n];
  float4 ph = *(const float4*)&phase[n];
  float omv[4] = {TWO_PI_F * fr.x, TWO_PI_F * fr.y, TWO_PI_F * fr.z, TWO_PI_F * fr.w};
  float dpv[4] = {dv.x, dv.y, dv.z, dv.w};
  float amv[4] = {am.x, am.y, am.z, am.w};
  float phv[4] = {ph.x, ph.y, ph.z, ph.w};
  float m00[4], m01[4], m10[4], m11[4], osc[4];
#pragma unroll
  for (int j = 0; j < 4; j++) {
    float osq = omv[j] * omv[j];
    m00[j] = 1.f - osq * DT * DT;  m01[j] = DT * (1.f - dpv[j] * DT);
    m10[j] = -osq * DT;            m11[j] = 1.f - dpv[j] * DT;
    osc[j] = amv[j] * sinf(omv[j] * DT + phv[j]);    // t = DT
  }

  float4 csv = *(const float4*)&carryS[c * NDIM + n];
  float4 cvv = *(const float4*)&carryV[c * NDIM + n];
  float hs[4] = {csv.x, csv.y, csv.z, csv.w};
  float hv[4] = {cvv.x, cvv.y, cvv.z, cvv.w};

  const unsigned short* zp = zpart + (size_t)c * CL * NDIM + n;
  float* op = out + (size_t)c * CL * NDIM + n;
#pragma unroll 4
  for (int i = 0; i < CL; i++) {
    ushort4 zv = *(const ushort4*)&zp[(size_t)i * NDIM];
    float z[4] = {bf2f(zv.x), bf2f(zv.y), bf2f(zv.z), bf2f(zv.w)};
    float o[4];
#pragma unroll
    for (int j = 0; j < 4; j++) {
      float t = m00[j] * hs[j] + m01[j] * hv[j];     // h = M h
      float u = m10[j] * hs[j] + m11[j] * hv[j];
      hs[j] = t; hv[j] = u;
      o[j] = fminf(1.f, fmaxf(-1.f, hs[j] + z[j] + osc[j]));
    }
    *(float4*)&op[(size_t)i * NDIM] = (float4){o[0], o[1], o[2], o[3]};
  }
}

// ============ FALLBACK PATH: exact round-7 pipeline (64 MiB ws) ============
__global__ __launch_bounds__(256, 2) void gemm_bt_kernel(
    const unsigned short* __restrict__ A,
    const unsigned short* __restrict__ Bm,
    const float* __restrict__ bias,
    unsigned short* __restrict__ C) {
  __shared__ __align__(16) unsigned short sA[128 * 32];
  __shared__ __align__(16) unsigned short sB[128 * 32];

  const int tid  = threadIdx.x;
  const int lane = tid & 63;
  const int wave = tid >> 6;
  const int wr = wave >> 1;
  const int wc = wave & 1;
  const int q  = lane >> 4;
  const int lm = lane & 15;

  const int bM = blockIdx.x * 128;
  const int bN = blockIdx.y * 128;

  f32x4 acc[4][4];
#pragma unroll
  for (int i = 0; i < 4; i++)
#pragma unroll
    for (int j = 0; j < 4; j++) acc[i][j] = (f32x4){0.f, 0.f, 0.f, 0.f};

  const int idx0 = tid;
  const int idx1 = tid + 256;
  const int r0 = idx0 >> 2, g0 = idx0 & 3;
  const int r1 = idx1 >> 2, g1 = idx1 & 3;
  const int dst0 = r0 * 32 + ((g0 ^ ((r0 >> 1) & 3)) * 8);
  const int dst1 = r1 * 32 + ((g1 ^ ((r1 >> 1) & 3)) * 8);
  const unsigned short* gA0 = A  + (size_t)(bM + r0) * KDIM + g0 * 8;
  const unsigned short* gA1 = A  + (size_t)(bM + r1) * KDIM + g1 * 8;
  const unsigned short* gB0 = Bm + (size_t)(bN + r0) * KDIM + g0 * 8;
  const unsigned short* gB1 = Bm + (size_t)(bN + r1) * KDIM + g1 * 8;
  const int rq = (q ^ ((lm >> 1) & 3)) * 8;

  for (int k0 = 0; k0 < KDIM; k0 += 32) {
    uint4 av0 = *(const uint4*)(gA0 + k0);
    uint4 av1 = *(const uint4*)(gA1 + k0);
    uint4 bv0 = *(const uint4*)(gB0 + k0);
    uint4 bv1 = *(const uint4*)(gB1 + k0);
    __syncthreads();
    *(uint4*)&sA[dst0] = av0;
    *(uint4*)&sA[dst1] = av1;
    *(uint4*)&sB[dst0] = bv0;
    *(uint4*)&sB[dst1] = bv1;
    __syncthreads();

    bf16x8 af[4], bfr[4];
#pragma unroll
    for (int mt = 0; mt < 4; mt++)
      af[mt]  = *(const bf16x8*)&sA[(wr * 64 + mt * 16 + lm) * 32 + rq];
#pragma unroll
    for (int nt = 0; nt < 4; nt++)
      bfr[nt] = *(const bf16x8*)&sB[(wc * 64 + nt * 16 + lm) * 32 + rq];

#pragma unroll
    for (int mt = 0; mt < 4; mt++)
#pragma unroll
      for (int nt = 0; nt < 4; nt++)
        acc[mt][nt] = __builtin_amdgcn_mfma_f32_16x16x32_bf16(
            af[mt], bfr[nt], acc[mt][nt], 0, 0, 0);
  }

#pragma unroll
  for (int nt = 0; nt < 4; nt++) {
    const int col = bN + wc * 64 + nt * 16 + lm;
    const float bz = bias[col];
#pragma unroll
    for (int mt = 0; mt < 4; mt++) {
      const int row0 = bM + wr * 64 + mt * 16 + q * 4;
#pragma unroll
      for (int r = 0; r < 4; r++)
        C[(size_t)(row0 + r) * NDIM + col] = f2bf(acc[mt][nt][r] + bz);
    }
  }
}

__global__ void scan_pass1(const unsigned short* __restrict__ force,
                           const float* __restrict__ freq,
                           const float* __restrict__ damp,
                           float* __restrict__ chunkS,
                           float* __restrict__ chunkV) {
  int gid = blockIdx.x * blockDim.x + threadIdx.x;
  int n4 = gid & (NDIM / 4 - 1);
  int c  = gid >> 10;
  int n  = n4 * 4;
  float4 fr = *(const float4*)&freq[n];
  float4 dv = *(const float4*)&damp[n];
  float osq[4] = {TWO_PI_F * fr.x, TWO_PI_F * fr.y, TWO_PI_F * fr.z, TWO_PI_F * fr.w};
  float dp[4]  = {dv.x, dv.y, dv.z, dv.w};
  float s[4] = {0.f, 0.f, 0.f, 0.f}, v[4] = {0.f, 0.f, 0.f, 0.f};
#pragma unroll
  for (int j = 0; j < 4; j++) osq[j] *= osq[j];
  const unsigned short* fp = force + (size_t)c * CL * NDIM + n;
#pragma unroll 4
  for (int i = 0; i < CL; i++) {
    ushort4 fv = *(const ushort4*)&fp[(size_t)i * NDIM];
    float f[4] = {bf2f(fv.x), bf2f(fv.y), bf2f(fv.z), bf2f(fv.w)};
#pragma unroll
    for (int j = 0; j < 4; j++) {
      float a = -osq[j] * s[j] - dp[j] * v[j] + f[j];
      v[j] += a * DT;
      s[j] += v[j] * DT;
    }
  }
  *(float4*)&chunkS[c * NDIM + n] = (float4){s[0], s[1], s[2], s[3]};
  *(float4*)&chunkV[c * NDIM + n] = (float4){v[0], v[1], v[2], v[3]};
}

__global__ void scan_pass2(const float* __restrict__ chunkS,
                           const float* __restrict__ chunkV,
                           const float* __restrict__ freq,
                           const float* __restrict__ damp,
                           float* __restrict__ carryS,
                           float* __restrict__ carryV) {
  int n = blockIdx.x * blockDim.x + threadIdx.x;
  float om = TWO_PI_F * freq[n];
  float osq = om * om;
  float dp = damp[n];
  float a00 = 1.f - osq * DT * DT, a01 = DT * (1.f - dp * DT);
  float a10 = -osq * DT,           a11 = 1.f - dp * DT;
#pragma unroll
  for (int i = 0; i < 6; i++) {
    float b00 = a00 * a00 + a01 * a10;
    float b01 = a00 * a01 + a01 * a11;
    float b10 = a10 * a00 + a11 * a10;
    float b11 = a10 * a01 + a11 * a11;
    a00 = b00; a01 = b01; a10 = b10; a11 = b11;
  }
  float cs = 0.f, cv = 0.f;
#pragma unroll 8
  for (int c = 0; c < CH; c++) {
    carryS[c * NDIM + n] = cs;
    carryV[c * NDIM + n] = cv;
    float ls = chunkS[c * NDIM + n];
    float lv = chunkV[c * NDIM + n];
    float ns = a00 * cs + a01 * cv + ls;
    float nv = a10 * cs + a11 * cv + lv;
    cs = ns; cv = nv;
  }
}

__global__ void scan_pass3(const unsigned short* __restrict__ force,
                           const float* __restrict__ amp,
                           const float* __restrict__ freq,
                           const float* __restrict__ phase,
                           const float* __restrict__ damp,
                           const float* __restrict__ carryS,
                           const float* __restrict__ carryV,
                           float* __restrict__ out) {
  int gid = blockIdx.x * blockDim.x + threadIdx.x;
  int n4 = gid & (NDIM / 4 - 1);
  int c  = gid >> 10;
  int n  = n4 * 4;
  float4 fr = *(const float4*)&freq[n];
  float4 dv = *(const float4*)&damp[n];
  float4 am = *(const float4*)&amp[n];
  float4 ph = *(const float4*)&phase[n];
  float om[4] = {TWO_PI_F * fr.x, TWO_PI_F * fr.y, TWO_PI_F * fr.z, TWO_PI_F * fr.w};
  float dp[4] = {dv.x, dv.y, dv.z, dv.w};
  float osq[4], osc[4], s[4], v[4];
  float amv[4] = {am.x, am.y, am.z, am.w};
  float phv[4] = {ph.x, ph.y, ph.z, ph.w};
#pragma unroll
  for (int j = 0; j < 4; j++) {
    osq[j] = om[j] * om[j];
    osc[j] = amv[j] * sinf(om[j] * DT + phv[j]);
  }
  float4 csv = *(const float4*)&carryS[c * NDIM + n];
  float4 cvv = *(const float4*)&carryV[c * NDIM + n];
  s[0] = csv.x; s[1] = csv.y; s[2] = csv.z; s[3] = csv.w;
  v[0] = cvv.x; v[1] = cvv.y; v[2] = cvv.z; v[3] = cvv.w;
  const unsigned short* fp = force + (size_t)c * CL * NDIM + n;
  float* op = out + (size_t)c * CL * NDIM + n;
#pragma unroll 4
  for (int i = 0; i < CL; i++) {
    ushort4 fv = *(const ushort4*)&fp[(size_t)i * NDIM];
    float f[4] = {bf2f(fv.x), bf2f(fv.y), bf2f(fv.z), bf2f(fv.w)};
    float o[4];
#pragma unroll
    for (int j = 0; j < 4; j++) {
      float a = -osq[j] * s[j] - dp[j] * v[j] + f[j];
      v[j] += a * DT;
      s[j] += v[j] * DT;
      o[j] = fminf(1.f, fmaxf(-1.f, s[j] + osc[j]));
    }
    *(float4*)&op[(size_t)i * NDIM] = (float4){o[0], o[1], o[2], o[3]};
  }
}

// ---------------- launch ----------------
extern "C" void kernel_launch(void* const* d_in, const int* in_sizes, int n_in,
                              void* d_out, int out_size, void* d_ws, size_t ws_size,
                              hipStream_t stream) {
  const float* x     = (const float*)d_in[0];
  const float* W     = (const float*)d_in[1];
  const float* bias  = (const float*)d_in[2];
  const float* amp   = (const float*)d_in[3];
  const float* freq  = (const float*)d_in[4];
  const float* phase = (const float*)d_in[5];
  const float* damp  = (const float*)d_in[6];

  const size_t MiB = 1024 * 1024;
  const int n4each = MDIM * KDIM / 4;
  dim3 gg(MDIM / 128, NDIM / 128);

  if (ws_size >= 66 * MiB) {
    // fused path (66 MiB, proven in R8):
    // xbf[0,16Mi) wbf[16,32Mi) zpart[32,64Mi) chunkS/V[64,66Mi)
    unsigned short* xbf   = (unsigned short*)d_ws;
    unsigned short* wbf   = xbf + (size_t)MDIM * KDIM;
    unsigned short* zpart = wbf + (size_t)NDIM * KDIM;
    float* chunkS = (float*)((char*)d_ws + 64 * MiB);
    float* chunkV = chunkS + CH * NDIM;

    cast2_bf16_kernel<<<(2 * n4each + 255) / 256, 256, 0, stream>>>(
        x, xbf, W, wbf, n4each);
    gemm_scan_kernel<<<gg, 256, 0, stream>>>(xbf, wbf, bias, freq, damp,
                                             zpart, chunkS, chunkV);
    scan_pass2_inplace<<<NDIM / 256, 256, 0, stream>>>(chunkS, chunkV,
                                                       freq, damp);
    // chunkS/V now hold carries (in-place)
    scan_out_carry<<<CH * NDIM / 4 / 256, 256, 0, stream>>>(
        zpart, amp, freq, phase, damp, chunkS, chunkV, (float*)d_out);
  } else {
    // fallback: exact round-7 pipeline (proven, 64 MiB)
    unsigned short* xbf   = (unsigned short*)d_ws;
    unsigned short* wbf   = xbf + (size_t)MDIM * KDIM;
    unsigned short* force = wbf + (size_t)NDIM * KDIM;
    float* chunkS = (float*)d_ws;            // aliases xbf: dead after GEMM
    float* chunkV = chunkS + CH * NDIM;
    float* carryS = chunkV + CH * NDIM;
    float* carryV = carryS + CH * NDIM;

    cast2_bf16_kernel<<<(2 * n4each + 255) / 256, 256, 0, stream>>>(
        x, xbf, W, wbf, n4each);
    gemm_bt_kernel<<<gg, 256, 0, stream>>>(xbf, wbf, bias, force);
    scan_pass1<<<CH * NDIM / 4 / 256, 256, 0, stream>>>(force, freq, damp,
                                                        chunkS, chunkV);
    scan_pass2<<<NDIM / 256, 256, 0, stream>>>(chunkS, chunkV, freq, damp,
                                               carryS, carryV);
    scan_pass3<<<CH * NDIM / 4 / 256, 256, 0, stream>>>(
        force, amp, freq, phase, damp, carryS, carryV, (float*)d_out);
  }
}